// Round 1
// 566.081 us; speedup vs baseline: 1.0060x; 1.0060x over previous
//
#include <hip/hip_runtime.h>
#include <hip/hip_bf16.h>
#include <math.h>

#define EMB 768
#define DFF 3072
#define HEADS 12
#define HD 64
#define LSEQ 1024
#define BATCH 16
#define BL (BATCH * LSEQ)   // 16384 rows
#define QKVD 2304           // fused q|k|v column dim
#define QSCALE 0.1803368801111204f  // (1/sqrt(64)) * log2(e)

typedef __attribute__((ext_vector_type(8))) short short8;
typedef __attribute__((ext_vector_type(4))) float floatx4;
typedef unsigned short u16;

__device__ __forceinline__ u16 f2bf(float f) {
  union { float f; unsigned u; } c; c.f = f;
  unsigned u = c.u;
  u += 0x7fffu + ((u >> 16) & 1u);   // round-to-nearest-even
  return (u16)(u >> 16);
}
__device__ __forceinline__ u16 f2bf_trunc(float f) {  // cheap: 1 op, ~0.4% err
  union { float f; unsigned u; } c; c.f = f;
  return (u16)(c.u >> 16);
}
__device__ __forceinline__ float fast_exp2(float x) {
#if __has_builtin(__builtin_amdgcn_exp2f)
  return __builtin_amdgcn_exp2f(x);
#else
  return exp2f(x);
#endif
}
__device__ __forceinline__ float fast_rcp(float x) {
#if __has_builtin(__builtin_amdgcn_rcpf)
  return __builtin_amdgcn_rcpf(x);
#else
  return 1.0f / x;
#endif
}
// gelu exact-erf replacement: tanh form via exp2; |err| <~1e-3, clamped safe
__device__ __forceinline__ float gelu_fast(float x) {
  float x2 = x * x;
  float u = x * fmaf(0.10294540f, x2, 2.30211423f);  // = 2*log2e*0.7978846*(x+0.044715x^3)
  u = fminf(fmaxf(u, -30.f), 30.f);
  float t = fast_exp2(u);
  return x * t * fast_rcp(t + 1.0f);                  // x * sigmoid(2v)
}
// async global->LDS, 16B per lane; lds dest = wave-uniform base + lane*16
__device__ __forceinline__ void async16(const u16* g, u16* l) {
  __builtin_amdgcn_global_load_lds(
      (const __attribute__((address_space(1))) unsigned int*)g,
      (__attribute__((address_space(3))) unsigned int*)l, 16, 0, 0);
}
__device__ __forceinline__ short8 load16(const u16* p) {
  return *reinterpret_cast<const short8*>(p);
}

// ---------------- LayerNorm: fp32 in -> bf16 out (one wave per row) ----------
__global__ __launch_bounds__(256) void ln_kernel(const float* __restrict__ x,
                                                 const float* __restrict__ g,
                                                 const float* __restrict__ b,
                                                 u16* __restrict__ out) {
  int row = blockIdx.x * 4 + (threadIdx.x >> 6);
  int lane = threadIdx.x & 63;
  const float* xr = x + (size_t)row * EMB;
  float v[12];
#pragma unroll
  for (int i = 0; i < 3; i++) {
    float4 t = *reinterpret_cast<const float4*>(xr + i * 256 + lane * 4);
    v[i*4+0] = t.x; v[i*4+1] = t.y; v[i*4+2] = t.z; v[i*4+3] = t.w;
  }
  float s = 0.f, ss = 0.f;
#pragma unroll
  for (int i = 0; i < 12; i++) { s += v[i]; ss += v[i] * v[i]; }
#pragma unroll
  for (int off = 1; off < 64; off <<= 1) {
    s  += __shfl_xor(s, off);
    ss += __shfl_xor(ss, off);
  }
  float mu  = s * (1.f / 768.f);
  float var = ss * (1.f / 768.f) - mu * mu;
  float rs  = rsqrtf(var + 1e-5f);
  u16* orow = out + (size_t)row * EMB;
#pragma unroll
  for (int i = 0; i < 3; i++) {
    int col = i * 256 + lane * 4;
    ushort4 o;
    o.x = f2bf((v[i*4+0] - mu) * rs * g[col+0] + b[col+0]);
    o.y = f2bf((v[i*4+1] - mu) * rs * g[col+1] + b[col+1]);
    o.z = f2bf((v[i*4+2] - mu) * rs * g[col+2] + b[col+2]);
    o.w = f2bf((v[i*4+3] - mu) * rs * g[col+3] + b[col+3]);
    *reinterpret_cast<ushort4*>(orow + col) = o;
  }
}

// -------- fused prep: 6 weight transposes (fp32 (K,N) -> bf16 (N,K)) + bias --
// flat grid: [0,2304) Wq/Wk/Wv/Wo (576 each), [2304,4608) W1, [4608,6912) W2,
// [6912,6921) qkv bias concat. threads (32,8).
__global__ void prep_kernel(const float* __restrict__ Wq, const float* __restrict__ Wk,
                            const float* __restrict__ Wv, const float* __restrict__ Wo,
                            const float* __restrict__ W1, const float* __restrict__ W2,
                            u16* __restrict__ wqkv, u16* __restrict__ wot,
                            u16* __restrict__ w1t, u16* __restrict__ w2t,
                            const float* __restrict__ bq, const float* __restrict__ bk,
                            const float* __restrict__ bv, float* __restrict__ obias) {
  __shared__ float t[32][33];
  int id = blockIdx.x;
  int tx = threadIdx.x, ty = threadIdx.y;
  if (id >= 6912) {  // bias concat: 9 blocks x 256 threads
    int i = (id - 6912) * 256 + ty * 32 + tx;
    if (i < QKVD)
      obias[i] = i < EMB ? bq[i] : (i < 2*EMB ? bk[i - EMB] : bv[i - 2*EMB]);
    return;
  }
  const float* in; u16* out; int K, N, bx, by;
  if (id < 2304) {
    int seg = id / 576, rem = id % 576;
    bx = rem % 24; by = rem / 24; K = EMB; N = EMB;
    in = seg == 0 ? Wq : seg == 1 ? Wk : seg == 2 ? Wv : Wo;
    out = seg == 3 ? wot : wqkv + (size_t)seg * EMB * EMB;
  } else if (id < 4608) {
    int rem = id - 2304; bx = rem % 96; by = rem / 96;
    in = W1; out = w1t; K = EMB; N = DFF;
  } else {
    int rem = id - 4608; bx = rem % 24; by = rem / 24;
    in = W2; out = w2t; K = DFF; N = EMB;
  }
  int x0 = bx * 32, y0 = by * 32;
#pragma unroll
  for (int i = 0; i < 4; i++)
    t[ty + i*8][tx] = in[(size_t)(y0 + ty + i*8) * N + x0 + tx];
  __syncthreads();
#pragma unroll
  for (int i = 0; i < 4; i++)
    out[(size_t)(x0 + ty + i*8) * K + y0 + tx] = f2bf(t[tx][ty + i*8]);
}

// -------- V transpose (bf16): qkv (b,l,1536+h*64+d) -> (b,h,d,l) ------------
__global__ void vtrans_kernel(const u16* __restrict__ qkv, u16* __restrict__ vt) {
  __shared__ u16 t[32][33];
  int l0 = blockIdx.x * 32;
  int d0 = blockIdx.y * 32;
  int bh = blockIdx.z;
  int b = bh / HEADS, h = bh % HEADS;
  int tx = threadIdx.x, ty = threadIdx.y;  // 32 x 8
#pragma unroll
  for (int i = 0; i < 4; i++)
    t[ty + i*8][tx] = qkv[(size_t)(b * LSEQ + l0 + ty + i*8) * QKVD + 2*EMB + h * HD + d0 + tx];
  __syncthreads();
#pragma unroll
  for (int i = 0; i < 4; i++)
    vt[(size_t)(bh * HD + d0 + ty + i*8) * LSEQ + l0 + tx] = t[tx][ty + i*8];
}

// -------- GEMM: C = A(MxK,bf16) @ Bt(NxK,bf16)^T + bias, fused epilogue -----
// BK=64, global_load_lds 16B staging with XOR-swizzled source columns:
// LDS chunk (row r, c8) lives at position c8^(r&7) -> conflict-free b128 reads.
// MFMA operands SWAPPED (bfr, af): C^T layout => lane holds m=l16 and 4
// consecutive n = nbase+lhi*4..+3 in regs -> vectorized bias/res/store.
// mode 0: out bf16 = (acc + bias) * (n<scale_n ? scale : 1)
// mode 1: out fp32 = acc + bias + res
// mode 2: out bf16 = gelu(acc + bias)
#define BK 64
__global__ __launch_bounds__(256) void gemm_kernel(
    const u16* __restrict__ A, const u16* __restrict__ Bt,
    const float* __restrict__ bias, const float* __restrict__ res,
    u16* __restrict__ outb, float* __restrict__ outf,
    int M, int N, int K, int mode, float scale, int scale_n) {
  __shared__ u16 As[128 * BK];
  __shared__ u16 Bs[128 * BK];
  int tid = threadIdx.x;
  int lane = tid & 63, wave = tid >> 6;
  int wm = wave & 1, wn = wave >> 1;        // 2x2 wave grid
  int l16 = lane & 15, lhi = lane >> 4;
  int m0 = blockIdx.x * 128, n0 = blockIdx.y * 128;

  floatx4 acc[4][4];
#pragma unroll
  for (int i = 0; i < 4; i++)
#pragma unroll
    for (int j = 0; j < 4; j++) acc[i][j] = {0.f, 0.f, 0.f, 0.f};

  // ---- staging setup: one async16 covers 8 rows x 8 chunks (1024 B)
  int rr = lane >> 3;                       // row within 8-row group
  int cs = ((lane & 7) ^ rr) * 8;           // swizzled source col (shorts)
  const u16* aptr = A + (size_t)(m0 + wave * 32 + rr) * K + cs;
  const u16* bptr = Bt + (size_t)(n0 + wave * 32 + rr) * K + cs;
  u16* asl = As + (wave * 32) * BK;         // wave-uniform LDS bases
  u16* bsl = Bs + (wave * 32) * BK;

  // ---- read setup: chunk (r,c8) is at r*64 + (c8^(r&7))*8 shorts
  int l7 = l16 & 7;
  int oa0 = (wm * 64 + l16) * BK + ((lhi ^ l7) * 8);     // kk=0: c8=lhi
  int ob0 = (wn * 64 + l16) * BK + ((lhi ^ l7) * 8);
  int oa1 = oa0 ^ 32;                                     // kk=1: c8=lhi^4 -> ^(4*8)
  int ob1 = ob0 ^ 32;

  for (int k0 = 0; k0 < K; k0 += BK) {
    __syncthreads();
#pragma unroll
    for (int i = 0; i < 4; i++) {
      async16(aptr + (size_t)(i * 8) * K + k0, asl + i * 8 * BK);
      async16(bptr + (size_t)(i * 8) * K + k0, bsl + i * 8 * BK);
    }
    __syncthreads();
#pragma unroll
    for (int kk = 0; kk < 2; kk++) {
      int oA = kk ? oa1 : oa0;
      int oB = kk ? ob1 : ob0;
      short8 af[4], bfr[4];
#pragma unroll
      for (int mt = 0; mt < 4; mt++)
        af[mt] = *reinterpret_cast<const short8*>(&As[oA + mt * 16 * BK]);
#pragma unroll
      for (int nt = 0; nt < 4; nt++)
        bfr[nt] = *reinterpret_cast<const short8*>(&Bs[oB + nt * 16 * BK]);
#pragma unroll
      for (int mt = 0; mt < 4; mt++)
#pragma unroll
        for (int nt = 0; nt < 4; nt++)
          acc[mt][nt] = __builtin_amdgcn_mfma_f32_16x16x32_bf16(bfr[nt], af[mt],
                                                                acc[mt][nt], 0, 0, 0);
    }
  }

  // epilogue: lane has row m, cols nbase..nbase+3 in acc[mt][nt][0..3]
#pragma unroll
  for (int mt = 0; mt < 4; mt++) {
    int m = m0 + wm*64 + mt*16 + l16;
#pragma unroll
    for (int nt = 0; nt < 4; nt++) {
      int nbase = n0 + wn*64 + nt*16 + lhi*4;
      float4 bv = *reinterpret_cast<const float4*>(&bias[nbase]);
      float v0 = acc[mt][nt][0] + bv.x, v1 = acc[mt][nt][1] + bv.y;
      float v2 = acc[mt][nt][2] + bv.z, v3 = acc[mt][nt][3] + bv.w;
      if (mode == 1) {
        float4 r = *reinterpret_cast<const float4*>(&res[(size_t)m * N + nbase]);
        float4 o; o.x = v0 + r.x; o.y = v1 + r.y; o.z = v2 + r.z; o.w = v3 + r.w;
        *reinterpret_cast<float4*>(&outf[(size_t)m * N + nbase]) = o;
      } else {
        if (mode == 2) {
          v0 = gelu_fast(v0); v1 = gelu_fast(v1);
          v2 = gelu_fast(v2); v3 = gelu_fast(v3);
        } else {
          float sc = (nbase < scale_n) ? scale : 1.0f;
          v0 *= sc; v1 *= sc; v2 *= sc; v3 *= sc;
        }
        ushort4 o;
        o.x = f2bf(v0); o.y = f2bf(v1); o.z = f2bf(v2); o.w = f2bf(v3);
        *reinterpret_cast<ushort4*>(&outb[(size_t)m * N + nbase]) = o;
      }
    }
  }
}

// -------- Flash attention: LDS-staged K/V, double-buffered prefetch ---------
// K/V tile (64 seq x 64 d) staged ONCE per block (was 4x redundant per-wave
// global loads) via global_load_lds with the same XOR source-swizzle as the
// GEMM (chunk (r,c8) at slot c8^(r&7) -> conflict-free b128 reads).
// Stage for tile t+1 issued at TOP of tile t's compute; the single
// __syncthreads() per iteration rotates buffers and its implicit vmcnt(0)
// drain lands ~2-3k cycles after issue -> global latency fully hidden.
// S^T = K.Q^T; P exits with 4 consecutive seq per lane -> b64 P writes, b128
// P^T reads; O^T = V^T.P^T.
#define PSTRIDE 76
__global__ __launch_bounds__(256) void flash_kernel(
    const u16* __restrict__ qkv, const u16* __restrict__ vt,
    u16* __restrict__ ctx) {
  __shared__ u16 Kb[2][64 * 64];
  __shared__ u16 Vb[2][64 * 64];
  __shared__ u16 Ps[4][2][16][PSTRIDE];
  int tid = threadIdx.x;
  int lane = tid & 63, w = tid >> 6;
  int l16 = lane & 15, lhi = lane >> 4;

  int i = blockIdx.x;                      // 768 = 4 qb x 192 bh, XCD-affine
  int bh = (i & 7) | ((i >> 5) << 3);      // blocks with equal (i&7, i>>5) share bh
  int qb = (i >> 3) & 3;
  int b = bh / HEADS, h = bh % HEADS;
  int q0 = qb * 256 + w * 64;              // wave's 64 q-rows

  const u16* qbase = qkv + (size_t)(b * LSEQ) * QKVD + h * HD;
  const u16* kbase = qbase + EMB;
  const u16* vbase = vt + (size_t)(bh * HD) * LSEQ;

  // ---- staging setup: wave w covers rows w*16..w*16+15 of each 64-row tile
  int rr = lane >> 3;                       // row within 8-row group
  int c8 = (lane & 7) ^ rr;                 // swizzled source chunk (8 u16)
  const u16* ksrc = kbase + (size_t)(w * 16 + rr) * QKVD + c8 * 8;
  const u16* vsrc = vbase + (size_t)(w * 16 + rr) * LSEQ + c8 * 8;

  // prologue: stage tile 0 into buffer 0
#pragma unroll
  for (int j = 0; j < 2; j++) {
    async16(ksrc + (size_t)(j * 8) * QKVD, &Kb[0][(w * 16 + j * 8) * 64]);
    async16(vsrc + (size_t)(j * 8) * LSEQ, &Vb[0][(w * 16 + j * 8) * 64]);
  }

  // Q^T B-fragments, resident: qf[st][kk] (st = q-subtile of 16)
  short8 qf[4][2];
#pragma unroll
  for (int st = 0; st < 4; st++)
#pragma unroll
    for (int kk = 0; kk < 2; kk++)
      qf[st][kk] = load16(qbase + (size_t)(q0 + st*16 + l16) * QKVD + kk*32 + lhi*8);

  floatx4 o[4][4];                          // o[st][mt]: O^T (d=mt*16+lhi*4+r, q=st*16+l16)
#pragma unroll
  for (int st = 0; st < 4; st++)
#pragma unroll
    for (int mt = 0; mt < 4; mt++) o[st][mt] = {0.f, 0.f, 0.f, 0.f};
  float l_i[4] = {0.f, 0.f, 0.f, 0.f};

  __syncthreads();                          // tile 0 landed (vmcnt drain)

  int cur = 0;
  for (int kt = 0; kt < LSEQ; kt += 64) {
    // stage tile kt+64 into buf[cur^1] (issued early, drained at loop barrier)
    if (kt + 64 < LSEQ) {
      const u16* kn = ksrc + (size_t)(kt + 64) * QKVD;
      const u16* vn = vsrc + (kt + 64);
#pragma unroll
      for (int j = 0; j < 2; j++) {
        async16(kn + (size_t)(j * 8) * QKVD, &Kb[cur ^ 1][(w * 16 + j * 8) * 64]);
        async16(vn + (size_t)(j * 8) * LSEQ, &Vb[cur ^ 1][(w * 16 + j * 8) * 64]);
      }
    }

    // K A-fragments (m=seq, k=d) and V^T A-fragments (m=d, k=seq) from LDS
    short8 kf[4][2], vf[4][2];
#pragma unroll
    for (int mt = 0; mt < 4; mt++) {
      int krow = mt * 16 + l16;             // K: seq-in-tile; V: d
#pragma unroll
      for (int kk = 0; kk < 2; kk++) {
        int slot = ((kk * 4 + lhi) ^ (krow & 7)) * 8;
        kf[mt][kk] = load16(&Kb[cur][krow * 64 + slot]);
        vf[mt][kk] = load16(&Vb[cur][krow * 64 + slot]);
      }
    }

#pragma unroll
    for (int st = 0; st < 4; st++) {
      u16* pbuf = &Ps[w][st & 1][0][0];
      floatx4 s[4];
#pragma unroll
      for (int mt = 0; mt < 4; mt++) s[mt] = {0.f, 0.f, 0.f, 0.f};
#pragma unroll
      for (int mt = 0; mt < 4; mt++)
#pragma unroll
        for (int kk = 0; kk < 2; kk++)
          s[mt] = __builtin_amdgcn_mfma_f32_16x16x32_bf16(kf[mt][kk], qf[st][kk],
                                                          s[mt], 0, 0, 0);
      // p = exp2(s); lane-local row partial (q = l16 fixed for this lane)
      float ls = 0.f;
#pragma unroll
      for (int mt = 0; mt < 4; mt++) {
        ushort4 pw;
        float p0 = fast_exp2(s[mt][0]), p1 = fast_exp2(s[mt][1]);
        float p2 = fast_exp2(s[mt][2]), p3 = fast_exp2(s[mt][3]);
        ls += (p0 + p1) + (p2 + p3);
        pw.x = f2bf_trunc(p0); pw.y = f2bf_trunc(p1);
        pw.z = f2bf_trunc(p2); pw.w = f2bf_trunc(p3);
        *reinterpret_cast<ushort4*>(&pbuf[l16 * PSTRIDE + mt*16 + lhi*4]) = pw;
      }
      l_i[st] += ls;
      // P^T B-fragments (k=seq, n=q) — contiguous b128
      short8 pf0 = load16(&pbuf[l16 * PSTRIDE + 0*32 + lhi*8]);
      short8 pf1 = load16(&pbuf[l16 * PSTRIDE + 1*32 + lhi*8]);
#pragma unroll
      for (int mt = 0; mt < 4; mt++) {
        o[st][mt] = __builtin_amdgcn_mfma_f32_16x16x32_bf16(vf[mt][0], pf0,
                                                            o[st][mt], 0, 0, 0);
        o[st][mt] = __builtin_amdgcn_mfma_f32_16x16x32_bf16(vf[mt][1], pf1,
                                                            o[st][mt], 0, 0, 0);
      }
    }

    __syncthreads();                        // buffer rotate + stage drain
    cur ^= 1;
  }

  // reduce row sums across the 4 lhi groups (lanes 16/32/48 apart)
#pragma unroll
  for (int st = 0; st < 4; st++) {
    l_i[st] += __shfl_xor(l_i[st], 16);
    l_i[st] += __shfl_xor(l_i[st], 32);
  }

#pragma unroll
  for (int st = 0; st < 4; st++) {
    float inv = fast_rcp(l_i[st]);
    size_t rowbase = (size_t)(b * LSEQ + q0 + st*16 + l16) * EMB + h * HD;
#pragma unroll
    for (int mt = 0; mt < 4; mt++) {
      ushort4 ow;
      ow.x = f2bf(o[st][mt][0] * inv); ow.y = f2bf(o[st][mt][1] * inv);
      ow.z = f2bf(o[st][mt][2] * inv); ow.w = f2bf(o[st][mt][3] * inv);
      *reinterpret_cast<ushort4*>(&ctx[rowbase + mt*16 + lhi*4]) = ow;
    }
  }
}

extern "C" void kernel_launch(void* const* d_in, const int* in_sizes, int n_in,
                              void* d_out, int out_size, void* d_ws, size_t ws_size,
                              hipStream_t stream) {
  const float* x    = (const float*)d_in[0];
  const float* ln1g = (const float*)d_in[1];
  const float* ln1b = (const float*)d_in[2];
  const float* Wq   = (const float*)d_in[3];
  const float* bq   = (const float*)d_in[4];
  const float* Wk   = (const float*)d_in[5];
  const float* bk   = (const float*)d_in[6];
  const float* Wv   = (const float*)d_in[7];
  const float* bv   = (const float*)d_in[8];
  const float* Wo   = (const float*)d_in[9];
  const float* bo   = (const float*)d_in[10];
  const float* ln2g = (const float*)d_in[11];
  const float* ln2b = (const float*)d_in[12];
  const float* W1   = (const float*)d_in[13];
  const float* b1   = (const float*)d_in[14];
  const float* W2   = (const float*)d_in[15];
  const float* b2   = (const float*)d_in[16];

  char* ws = (char*)d_ws;
  // activations
  u16* qkv_bf = (u16*)(ws);                               // [BL][2304]  75.5 MB
  u16* vt_bf  = (u16*)(ws + (size_t)75497472);            // [192*64][1024] 25.2 MB
  u16* h_bf   = (u16*)(ws + (size_t)100663296);           // [BL][768]   25.2 MB
  float* x2   = (float*)(ws + (size_t)125829120);         // [BL][768]f32 50.3 MB
  u16* m_bf   = (u16*)(ws);                               // [BL][3072] aliases qkv+vt
  // weights (bf16, transposed)
  char* wp = ws + (size_t)176160768;
  u16* wqkv = (u16*)(wp);                                 // [2304][768]
  u16* wot  = (u16*)(wp + (size_t)3538944);
  u16* w1t  = (u16*)(wp + (size_t)3538944 + 1179648);     // [3072][768]
  u16* w2t  = (u16*)(wp + (size_t)3538944 + 1179648 + 4718592); // [768][3072]
  float* qkvbias = (float*)(wp + (size_t)3538944 + 1179648 + 2*4718592);

  dim3 b256(256), tb(32, 8);

  prep_kernel<<<dim3(6921), tb, 0, stream>>>(Wq, Wk, Wv, Wo, W1, W2,
      wqkv, wot, w1t, w2t, bq, bk, bv, qkvbias);

  ln_kernel<<<dim3(BL/4), b256, 0, stream>>>(x, ln1g, ln1b, h_bf);

  // fused QKV: N=2304; q columns get QSCALE folded in (softmax exp2 domain)
  gemm_kernel<<<dim3(128, 18), b256, 0, stream>>>(h_bf, wqkv, qkvbias, nullptr,
      qkv_bf, nullptr, BL, QKVD, EMB, 0, QSCALE, EMB);

  vtrans_kernel<<<dim3(32, 2, BATCH*HEADS), tb, 0, stream>>>(qkv_bf, vt_bf);

  flash_kernel<<<dim3(768), b256, 0, stream>>>(qkv_bf, vt_bf, h_bf);

  gemm_kernel<<<dim3(128, 6), b256, 0, stream>>>(h_bf, wot, bo, x, nullptr, x2,
      BL, EMB, EMB, 1, 1.0f, 0);

  ln_kernel<<<dim3(BL/4), b256, 0, stream>>>(x2, ln2g, ln2b, h_bf);

  gemm_kernel<<<dim3(128, 24), b256, 0, stream>>>(h_bf, w1t, b1, nullptr, m_bf,
      nullptr, BL, DFF, EMB, 2, 1.0f, 0);

  gemm_kernel<<<dim3(128, 6), b256, 0, stream>>>(m_bf, w2t, b2, x2, nullptr,
      (float*)d_out, BL, EMB, DFF, 1, 1.0f, 0);
}